// Round 8
// baseline (173.067 us; speedup 1.0000x reference)
//
#include <hip/hip_runtime.h>
#include <hip/hip_bf16.h>
#include <math.h>

// ---------------------------------------------------------------------------
// Round 15: r13 (best known good: 114us, passed) + CLEAN barrier-halving.
// r14 post-mortem: raw-asm MFMA broke numerics (absmax 4.9) -- non-volatile
// asm + opaque hazard info => compiler's MFMA<->VALU hazard handling lost.
// Reverted; builtin MFMA only.
// r13 accounting: 5.4K cyc/phase vs ~2.6-3K of issue work => ~2x residue
// attributed to per-phase rendezvous (waitcnt drain + s_barrier + skew),
// 51 barriers/role. r11's pair attempt conflated interleaving (spill) and
// symmetric setprio; the clean test never ran. This round:
//   TILE PAIRS, STRICTLY SEQUENTIAL BODIES: producer phase j completes
//   tile 2j then tile 2j+1 (no interleave -> zero added live state),
//   writes slots 0/4096 of parity j&1; 26 barriers instead of 51.
//   Consumer lag-1 mirrors, tail-consumes tile 50 after final barrier.
//   Barrier counts match 26/26.
//   LDS: hshT (prologue-only) overlaid with vs4 (loop-only) -> ~39KB,
//   keeps 4 blocks/CU despite 16KB paired Y2.
// All else verbatim r13 (no-shuffle vs4, fp32 bias tables, asym setprio).
// Numerics: identical chain to r13; absmax ~0.125 vs thr 0.4725.
// ---------------------------------------------------------------------------

#define B_N    16384
#define KQ     51
#define HD     128
#define IND    64
#define BLK    128               // 2 waves: producer + consumer
#define RPB    16                // b-rows per block
#define GRID   (B_N / RPB)       // 1024
#define TPB    ((RPB * KQ) / 16) // 51 tiles per block (exact)
#define NPAIR  26                // pair j covers tiles 2j, 2j+1 (last: 50 only)

typedef __attribute__((ext_vector_type(8))) short short8;
typedef __attribute__((ext_vector_type(4))) float f32x4;

union S8U { short8 s8; unsigned u[4]; };

__device__ __forceinline__ unsigned short f2bf(float f) {
    __hip_bfloat16 t = __float2bfloat16(f);
    return *reinterpret_cast<unsigned short*>(&t);
}

#if defined(__gfx950__) && defined(__has_builtin)
#if __has_builtin(__builtin_amdgcn_cvt_pk_bf16_f32)
#define HAVE_PK_BF16 1
#endif
#endif

__device__ __forceinline__ unsigned pk_bf16(float lo, float hi) {
#ifdef HAVE_PK_BF16
    typedef __attribute__((ext_vector_type(2))) __bf16 bfv2;
    bfv2 r = __builtin_amdgcn_cvt_pk_bf16_f32(lo, hi);
    return *reinterpret_cast<unsigned*>(&r);
#else
    return (unsigned)f2bf(lo) | ((unsigned)f2bf(hi) << 16);
#endif
}

__launch_bounds__(BLK, 2)
__global__ void umnn_fused(const float* __restrict__ x,  const float* __restrict__ h,
                           const float* __restrict__ W1, const float* __restrict__ b1,
                           const float* __restrict__ W2, const float* __restrict__ b2,
                           const float* __restrict__ W3, const float* __restrict__ b3,
                           const float* __restrict__ W4, const float* __restrict__ b4,
                           float* __restrict__ out)
{
    __shared__ __align__(16) float hpL[RPB * HD];      // 8 KB block hpart
    __shared__ __align__(16) char  y2x[2][8192];       // 16 KB: 2 parities x 2 slots
    __shared__ __align__(16) float poolF[TPB * 64];    // 12.75 KB overlay:
                                                       //   prologue: hshT[63*20]
                                                       //   loop:     vs4[TPB*64]
    __shared__ __align__(16) float b2f[HD], b3f[HD];   // 1 KB fp32 bias tables
    __shared__ float xL[RPB];
    __shared__ float sSteps[KQ], sCcw[KQ];
    __shared__ float red2[2];

    float* hshT = poolF;                               // prologue-only
    float* vs4  = poolF;                               // loop-only (after B2)

    const int tid  = threadIdx.x;
    const int w    = tid >> 6;
    const int lane = tid & 63;
    const int q    = lane >> 4;
    const int lm   = lane & 15;
    const int swz  = lm & 7;
    const int rowBase = blockIdx.x * RPB;

    // ---- CC tables (validated r4 formula) ----
    if (tid < KQ) {
        const int j = tid;
        const float pi50 = 0.06283185307179586f;
        sSteps[j] = __cosf((float)j * pi50);
        float s = 0.0f;
        for (int i = 0; i <= 50; i += 2) {
            float Wi = (i == 0) ? 1.0f : 2.0f / (1.0f - (float)(i * i));
            float lam;
            if (j == 0) lam = 0.5f;
            else {
                int mp = (i * j) % 100;
                lam = __cosf((float)mp * pi50);
                if (j == 50) lam *= 0.5f;
            }
            s += (lam * 0.04f) * Wi;
        }
        sCcw[j] = s;
    }
    // ---- fp32 bias tables ----
    if (tid < HD) {
        b2f[tid] = b2[tid];
        b3f[tid] = b3[tid];
    }
    // ---- xmax scan (x: 64 KB, cache-resident) ----
    {
        const f32x4* x4 = (const f32x4*)x;
        float mx = -1e30f;
        for (int i = tid; i < B_N / 4; i += BLK) {
            f32x4 v = x4[i];
            mx = fmaxf(fmaxf(mx, fmaxf(v[0], v[1])), fmaxf(v[2], v[3]));
        }
        #pragma unroll
        for (int d = 32; d > 0; d >>= 1) mx = fmaxf(mx, __shfl_xor(mx, d));
        if (lane == 0) red2[w] = mx;
    }
    // ---- stage h^T for this block's 16 rows; init xL ----
    for (int i = tid; i < RPB * 63; i += BLK) {
        int r = i / 63, d = i - r * 63;
        hshT[d * 20 + r] = h[rowBase * 63 + i];
    }
    if (tid < RPB) xL[tid] = x[rowBase + tid];
    __syncthreads();                                   // B1

    const float xmax = fmaxf(red2[0], red2[1]) + 10.0f;

    // ---- block hpart: thread tid = feature n, 16 row-accumulators ----
    {
        const int n = tid;
        float acc[RPB];
        const float b1v = b1[n];
        #pragma unroll
        for (int r = 0; r < RPB; ++r) acc[r] = b1v;
        const float* wr = W1 + n * IND + 1;
        #pragma unroll 1
        for (int d = 0; d < IND - 1; ++d) {
            float wv = wr[d];
            const float* ht = hshT + d * 20;
            #pragma unroll
            for (int rc = 0; rc < RPB / 4; ++rc) {
                f32x4 hv = *(const f32x4*)(ht + rc * 4);
                acc[rc * 4 + 0] = fmaf(wv, hv[0], acc[rc * 4 + 0]);
                acc[rc * 4 + 1] = fmaf(wv, hv[1], acc[rc * 4 + 1]);
                acc[rc * 4 + 2] = fmaf(wv, hv[2], acc[rc * 4 + 2]);
                acc[rc * 4 + 3] = fmaf(wv, hv[3], acc[rc * 4 + 3]);
            }
        }
        #pragma unroll
        for (int r = 0; r < RPB; ++r) hpL[r * HD + n] = acc[r];
    }
    __syncthreads();                                   // B2 (hpL ready; hshT dead)

    // per-lane C-init byte offset into bias table: feature nt*16+q*4
    const int bIoff = q * 16;                          // + nt*64 at use site

    if (w == 0) {
        // ================= PRODUCER: layer 1 + layer 2 =================
        __builtin_amdgcn_s_setprio(0);
        float w1x[32];
        #pragma unroll
        for (int kk = 0; kk < 4; ++kk)
            #pragma unroll
            for (int j = 0; j < 8; ++j)
                w1x[kk * 8 + j] = W1[(kk * 32 + q * 8 + j) * IND];

        short8 W2A[8][4];
        #pragma unroll
        for (int nt = 0; nt < 8; ++nt) {
            #pragma unroll
            for (int kk = 0; kk < 4; ++kk) {
                const float* p2 = W2 + (nt * 16 + lm) * HD + kk * 32 + q * 8;
                S8U a2;
                #pragma unroll
                for (int j = 0; j < 4; ++j)
                    a2.u[j] = pk_bf16(p2[2 * j], p2[2 * j + 1]);
                W2A[nt][kk] = a2.s8;
            }
        }
        int wrOff[8];
        #pragma unroll
        for (int nt = 0; nt < 8; ++nt)
            wrOff[nt] = lm * 256 + (((2 * nt + (q >> 1)) ^ swz) << 4) + ((q & 1) << 3);
        const char* b2c = (const char*)b2f;

        // full tile body: build Y1, 32 MFMA, relu+pack+write to dst
        auto produce = [&](int tt, char* dst) {
            const int s    = tt * 16 + lm;             // 0..815
            const unsigned row = (unsigned)s / KQ;     // 0..15
            const int k    = s - (int)row * KQ;
            const float x0 = xL[row];
            const float X  = fmaf((xmax - x0) * 0.5f, sSteps[k] + 1.0f, x0);
            short8 Y1[4];
            #pragma unroll
            for (int kk = 0; kk < 4; ++kk) {
                const float* hp = hpL + row * HD + kk * 32 + q * 8;
                f32x4 ha = *(const f32x4*)hp;
                f32x4 hb = *(const f32x4*)(hp + 4);
                S8U u;
                u.u[0] = pk_bf16(fmaxf(fmaf(X, w1x[kk*8+0], ha[0]), 0.f),
                                 fmaxf(fmaf(X, w1x[kk*8+1], ha[1]), 0.f));
                u.u[1] = pk_bf16(fmaxf(fmaf(X, w1x[kk*8+2], ha[2]), 0.f),
                                 fmaxf(fmaf(X, w1x[kk*8+3], ha[3]), 0.f));
                u.u[2] = pk_bf16(fmaxf(fmaf(X, w1x[kk*8+4], hb[0]), 0.f),
                                 fmaxf(fmaf(X, w1x[kk*8+5], hb[1]), 0.f));
                u.u[3] = pk_bf16(fmaxf(fmaf(X, w1x[kk*8+6], hb[2]), 0.f),
                                 fmaxf(fmaf(X, w1x[kk*8+7], hb[3]), 0.f));
                Y1[kk] = u.s8;
            }
            f32x4 C[8];
            #pragma unroll
            for (int nt = 0; nt < 8; ++nt)
                C[nt] = *(const f32x4*)(b2c + nt * 64 + bIoff);
            #pragma unroll
            for (int kk = 0; kk < 4; ++kk)
                #pragma unroll
                for (int nt = 0; nt < 8; ++nt)
                    C[nt] = __builtin_amdgcn_mfma_f32_16x16x32_bf16(W2A[nt][kk], Y1[kk], C[nt], 0, 0, 0);
            #pragma unroll
            for (int nt = 0; nt < 8; ++nt) {
                unsigned lo = pk_bf16(fmaxf(C[nt][0], 0.f), fmaxf(C[nt][1], 0.f));
                unsigned hi = pk_bf16(fmaxf(C[nt][2], 0.f), fmaxf(C[nt][3], 0.f));
                *(int2*)(dst + wrOff[nt]) = make_int2((int)lo, (int)hi);
            }
        };

        #pragma unroll 1
        for (int j = 0; j < NPAIR; ++j) {
            char* d2 = y2x[j & 1];
            const int t0 = 2 * j;
            produce(t0, d2);                           // sequential bodies:
            if (t0 + 1 < TPB) produce(t0 + 1, d2 + 4096);  // zero extra live state
            __syncthreads();                           // pair j ready
        }
    } else {
        // ================= CONSUMER: layer 3 + layer 4 =================
        __builtin_amdgcn_s_setprio(1);                 // consumer is critical
        short8 W3A[8][4];
        f32x4  W4c[8];
        #pragma unroll
        for (int nt = 0; nt < 8; ++nt) {
            #pragma unroll
            for (int kk = 0; kk < 4; ++kk) {
                const float* p3 = W3 + (nt * 16 + lm) * HD + kk * 32 + q * 8;
                S8U a3;
                #pragma unroll
                for (int j = 0; j < 4; ++j)
                    a3.u[j] = pk_bf16(p3[2 * j], p3[2 * j + 1]);
                W3A[nt][kk] = a3.s8;
            }
            W4c[nt] = *(const f32x4*)(W4 + nt * 16 + q * 4);
        }
        const float b4v = b4[0];
        int rdOff[4];
        #pragma unroll
        for (int kk = 0; kk < 4; ++kk)
            rdOff[kk] = lm * 256 + (((kk * 4 + q) ^ swz) << 4);
        const char* b3c = (const char*)b3f;

        // full tile body: read Y2, 32 MFMA, L4 per-lane partial -> vs4
        auto consume = [&](int tt, const char* src) {
            short8 Y2[4];
            #pragma unroll
            for (int kk = 0; kk < 4; ++kk)
                Y2[kk] = *(const short8*)(src + rdOff[kk]);
            f32x4 C[8];
            #pragma unroll
            for (int nt = 0; nt < 8; ++nt)
                C[nt] = *(const f32x4*)(b3c + nt * 64 + bIoff);
            #pragma unroll
            for (int kk = 0; kk < 4; ++kk)
                #pragma unroll
                for (int nt = 0; nt < 8; ++nt)
                    C[nt] = __builtin_amdgcn_mfma_f32_16x16x32_bf16(W3A[nt][kk], Y2[kk], C[nt], 0, 0, 0);
            float p = 0.f;
            #pragma unroll
            for (int nt = 0; nt < 8; ++nt) {
                p = fmaf(fmaxf(C[nt][0], 0.f), W4c[nt][0], p);
                p = fmaf(fmaxf(C[nt][1], 0.f), W4c[nt][1], p);
                p = fmaf(fmaxf(C[nt][2], 0.f), W4c[nt][2], p);
                p = fmaf(fmaxf(C[nt][3], 0.f), W4c[nt][3], p);
            }
            vs4[tt * 64 + lane] = p;                   // conflict-free
        };

        #pragma unroll 1
        for (int j = 0; j < NPAIR; ++j) {
            __syncthreads();                           // pair j ready / rendezvous
            if (j >= 1) {
                const int p = j - 1;                   // pairs 0..24: both full
                const char* s2 = y2x[p & 1];
                consume(2 * p, s2);
                consume(2 * p + 1, s2 + 4096);
            }
        }
        // tail: pair NPAIR-1 = tile 50 only (producer finished all writes)
        {
            const char* s2 = y2x[(NPAIR - 1) & 1];
            consume(2 * (NPAIR - 1), s2);
        }

        // ---- deferred epilogue: 4-way quarter sum + elu + ccw + reduce ----
        {
            const int r   = lane >> 2;                 // row 0..15
            const int sub = lane & 3;
            float a = 0.f;
            #pragma unroll 1
            for (int j = 0; j < 13; ++j) {
                int k = sub + 4 * j;
                if (k < KQ) {
                    int s   = r * KQ + k;
                    int tt  = s >> 4;
                    int lm2 = s & 15;
                    const float* vb = vs4 + tt * 64 + lm2;
                    float y4 = vb[0] + vb[16] + vb[32] + vb[48] + b4v;
                    float f  = (y4 > 0.f) ? (y4 + 1.f) : __expf(y4);
                    a = fmaf(f, sCcw[k], a);
                }
            }
            a += __shfl_xor(a, 1);
            a += __shfl_xor(a, 2);
            if (sub == 0)
                out[rowBase + r] = a * (xmax - xL[r]) * 0.5f;
        }
    }
}

// ---------------------------------------------------------------------------
extern "C" void kernel_launch(void* const* d_in, const int* in_sizes, int n_in,
                              void* d_out, int out_size, void* d_ws, size_t ws_size,
                              hipStream_t stream)
{
    const float* x  = (const float*)d_in[0];
    const float* h  = (const float*)d_in[1];
    const float* W1 = (const float*)d_in[2];
    const float* b1 = (const float*)d_in[3];
    const float* W2 = (const float*)d_in[4];
    const float* b2 = (const float*)d_in[5];
    const float* W3 = (const float*)d_in[6];
    const float* b3 = (const float*)d_in[7];
    const float* W4 = (const float*)d_in[8];
    const float* b4 = (const float*)d_in[9];
    float* out = (float*)d_out;

    umnn_fused<<<GRID, BLK, 0, stream>>>(x, h, W1, b1, W2, b2, W3, b3,
                                         W4, b4, out);
}